// Round 7
// baseline (107.901 us; speedup 1.0000x reference)
//
#include <hip/hip_runtime.h>

#define BB 4
#define NN 8192
#define BN (BB * NN)
#define ALPHA 5.0f
#define EPSF 1e-12f
#define BLOCK 256
#define QPT 8              // queries per thread
#define QB (BLOCK * QPT)   // 2048 queries per block
#define BIGF 1e30f

// prep: refs4[g] = (x, y, z, 0.5*||p||^2)
__global__ __launch_bounds__(BLOCK) void prep_kernel(
    const float* __restrict__ xyz, float4* __restrict__ refs4) {
  int g = blockIdx.x * BLOCK + threadIdx.x;  // 0..BN-1
  float x = xyz[3 * g + 0], y = xyz[3 * g + 1], z = xyz[3 * g + 2];
  float hpp = 0.5f * fmaf(x, x, fmaf(y, y, z * z));
  refs4[g] = make_float4(x, y, z, hpp);
}

__device__ __forceinline__ float rdlane(float v, int lane) {
  return __uint_as_float(__builtin_amdgcn_readlane(__float_as_uint(v), lane));
}

// pairs layout: pairs[s * BN + b*NN + q]   (values are d2/2)
// Ref broadcast via v_readlane: refs live in VGPRs (64/wave, loaded
// coalesced), broadcast register->SGPR with zero memory-pipe involvement.
template <int NSEG>
__global__ __launch_bounds__(BLOCK, 4) void knn_kernel(
    const float4* __restrict__ refs4, float2* __restrict__ pairs) {
  constexpr int SEG = NN / NSEG;
  constexpr int CHUNKS = NN / QB;
  int bid = blockIdx.x;
  int s = bid % NSEG;
  int rem = bid / NSEG;
  int qchunk = rem % CHUNKS;
  int b = rem / CHUNKS;

  const float4* __restrict__ qb4 = refs4 + (size_t)b * NN;

  float nqx[QPT], nqy[QPT], nqz[QPT], hq[QPT], m1[QPT], m2[QPT];
#pragma unroll
  for (int i = 0; i < QPT; i++) {
    int q = qchunk * QB + threadIdx.x + i * BLOCK;
    float4 qp = qb4[q];  // coalesced vector load
    nqx[i] = -qp.x;
    nqy[i] = -qp.y;
    nqz[i] = -qp.z;
    hq[i] = qp.w;
    m1[i] = BIGF;
    m2[i] = BIGF;
  }

  const float4* __restrict__ rp = qb4 + s * SEG;
  int lane = threadIdx.x & 63;

#pragma unroll 1
  for (int c = 0; c < SEG; c += 64) {
    float4 r = rp[c + lane];  // 64 refs -> this wave's VGPRs, coalesced
#pragma unroll 1
    for (int jb = 0; jb < 64; jb += 16) {
#pragma unroll
      for (int k = 0; k < 16; k++) {
        int j = jb + k;
        float sx = rdlane(r.x, j);
        float sy = rdlane(r.y, j);
        float sz = rdlane(r.z, j);
        float pw = rdlane(r.w, j);  // compiler v_mov's this to VGPR once
#pragma unroll
        for (int i = 0; i < QPT; i++) {
          // key = 0.5||p||^2 - q.p  (per-query shift by -hq preserves order)
          float t = fmaf(nqx[i], sx, pw);
          t = fmaf(nqy[i], sy, t);
          t = fmaf(nqz[i], sz, t);
          m2[i] = __builtin_amdgcn_fmed3f(t, m1[i], m2[i]);  // old m1
          m1[i] = fminf(m1[i], t);
        }
      }
    }
  }

#pragma unroll
  for (int i = 0; i < QPT; i++) {
    int q = qchunk * QB + threadIdx.x + i * BLOCK;
    pairs[(size_t)s * BN + b * NN + q] =
        make_float2(m1[i] + hq[i], m2[i] + hq[i]);  // un-shift -> d2/2
  }
}

// merge: one thread per point; 256 blocks x 128 threads.
#define MBLK 128
#define NPART (BN / MBLK)  // 256
template <int NSEG>
__global__ __launch_bounds__(MBLK) void merge_kernel(
    const float2* __restrict__ pairs, float* __restrict__ dsum,
    float* __restrict__ partial) {
  int g = blockIdx.x * MBLK + threadIdx.x;  // 0 .. BN-1
  float m1 = BIGF, m2 = BIGF;
#pragma unroll 8
  for (int s = 0; s < NSEG; s++) {
    float2 p = pairs[(size_t)s * BN + g];
    float n2 = __builtin_amdgcn_fmed3f(p.x, m1, m2);
    m1 = fminf(m1, p.x);
    m2 = n2;
    n2 = __builtin_amdgcn_fmed3f(p.y, m1, m2);
    m1 = fminf(m1, p.y);
    m2 = n2;
  }
  float ds = sqrtf(fmaxf(m1 + m1, EPSF)) + sqrtf(fmaxf(m2 + m2, EPSF));
  dsum[g] = ds;

  float v = ds;
#pragma unroll
  for (int off = 32; off > 0; off >>= 1) v += __shfl_down(v, off, 64);
  __shared__ float warp_sums[MBLK / 64];
  if ((threadIdx.x & 63) == 0) warp_sums[threadIdx.x >> 6] = v;
  __syncthreads();
  if (threadIdx.x == 0) {
    float t = 0.0f;
#pragma unroll
    for (int w = 0; w < MBLK / 64; w++) t += warp_sums[w];
    partial[blockIdx.x] = t;
  }
}

// loss: single block of 1024 threads.
#define LBLK 1024
__global__ __launch_bounds__(LBLK) void loss_kernel(
    const float* __restrict__ dsum, const float* __restrict__ partial,
    float* __restrict__ out) {
  __shared__ float s_avg[BB];
  if (threadIdx.x < NPART) {
    float v = partial[threadIdx.x];  // 64 consecutive partials per batch
#pragma unroll
    for (int off = 32; off > 0; off >>= 1) v += __shfl_down(v, off, 64);
    if ((threadIdx.x & 63) == 0) s_avg[threadIdx.x >> 6] = v * (ALPHA / NN);
  }
  __syncthreads();

  const float4* d4 = (const float4*)dsum;
  float acc = 0.0f;
#pragma unroll
  for (int it = 0; it < BN / (LBLK * 4); it++) {
    int idx = it * LBLK + threadIdx.x;  // float4 index
    float4 v = d4[idx];
    float thr = s_avg[idx >> 11];       // 2048 float4 per batch
    acc += (v.x > thr) ? v.x : 0.0f;
    acc += (v.y > thr) ? v.y : 0.0f;
    acc += (v.z > thr) ? v.z : 0.0f;
    acc += (v.w > thr) ? v.w : 0.0f;
  }
#pragma unroll
  for (int off = 32; off > 0; off >>= 1) acc += __shfl_down(acc, off, 64);
  __shared__ float warp_sums[LBLK / 64];
  if ((threadIdx.x & 63) == 0) warp_sums[threadIdx.x >> 6] = acc;
  __syncthreads();
  if (threadIdx.x == 0) {
    float t = 0.0f;
#pragma unroll
    for (int w = 0; w < LBLK / 64; w++) t += warp_sums[w];
    out[0] = t;
  }
}

template <int NSEG>
static void run(const float* xyz, float* out, void* d_ws, hipStream_t stream) {
  float2* pairs = (float2*)d_ws;
  float4* refs4 = (float4*)(pairs + (size_t)NSEG * BN);
  float* dsum = (float*)(refs4 + BN);
  float* partial = dsum + BN;
  prep_kernel<<<BN / BLOCK, BLOCK, 0, stream>>>(xyz, refs4);
  int grid1 = BB * (NN / QB) * NSEG;
  knn_kernel<NSEG><<<grid1, BLOCK, 0, stream>>>(refs4, pairs);
  merge_kernel<NSEG><<<BN / MBLK, MBLK, 0, stream>>>(pairs, dsum, partial);
  loss_kernel<<<1, LBLK, 0, stream>>>(dsum, partial, out);
}

extern "C" void kernel_launch(void* const* d_in, const int* in_sizes, int n_in,
                              void* d_out, int out_size, void* d_ws,
                              size_t ws_size, hipStream_t stream) {
  const float* xyz = (const float*)d_in[0];
  float* out = (float*)d_out;

  auto need = [](int nseg) {
    return (size_t)nseg * BN * sizeof(float2) + BN * sizeof(float4) +
           BN * sizeof(float) + NPART * sizeof(float);
  };
  if (ws_size >= need(32)) {
    run<32>(xyz, out, d_ws, stream);  // grid1 = 512 blocks, 2/CU
  } else if (ws_size >= need(16)) {
    run<16>(xyz, out, d_ws, stream);
  } else {
    run<8>(xyz, out, d_ws, stream);
  }
}

// Round 8
// 105.822 us; speedup vs baseline: 1.0197x; 1.0197x over previous
//
#include <hip/hip_runtime.h>

#define BB 4
#define NN 8192
#define BN (BB * NN)
#define ALPHA 5.0f
#define EPSF 1e-12f
#define BLOCK 256
#define QPT 16             // queries per thread (amortizes LDS reads)
#define QB (BLOCK * QPT)   // 4096 queries per block
#define BIGF 1e30f

// prep: refs4[g] = (x, y, z, 0.5*||p||^2)
__global__ __launch_bounds__(BLOCK) void prep_kernel(
    const float* __restrict__ xyz, float4* __restrict__ refs4) {
  int g = blockIdx.x * BLOCK + threadIdx.x;  // 0..BN-1
  float x = xyz[3 * g + 0], y = xyz[3 * g + 1], z = xyz[3 * g + 2];
  float hpp = 0.5f * fmaf(x, x, fmaf(y, y, z * z));
  refs4[g] = make_float4(x, y, z, hpp);
}

// pairs layout: pairs[s * BN + b*NN + q]   (values are d2/2)
template <int NSEG>
__global__ __launch_bounds__(BLOCK) void knn_kernel(
    const float4* __restrict__ refs4, float2* __restrict__ pairs) {
  constexpr int SEG = NN / NSEG;       // 128 at NSEG=64
  constexpr int CHUNKS = NN / QB;      // 2
  int bid = blockIdx.x;
  int s = bid % NSEG;
  int rem = bid / NSEG;
  int qchunk = rem % CHUNKS;
  int b = rem / CHUNKS;

  const float4* __restrict__ qb4 = refs4 + (size_t)b * NN;

  __shared__ float4 tile[SEG];
  for (int r0 = threadIdx.x; r0 < SEG; r0 += BLOCK)
    tile[r0] = qb4[s * SEG + r0];

  float nqx[QPT], nqy[QPT], nqz[QPT], hq[QPT], m1[QPT], m2[QPT];
#pragma unroll
  for (int i = 0; i < QPT; i++) {
    int q = qchunk * QB + threadIdx.x + i * BLOCK;
    float4 qp = qb4[q];  // coalesced vector load
    nqx[i] = -qp.x;
    nqy[i] = -qp.y;
    nqz[i] = -qp.z;
    hq[i] = qp.w;
    m1[i] = BIGF;
    m2[i] = BIGF;
  }
  __syncthreads();

#pragma unroll 2
  for (int j = 0; j < SEG; j++) {
    float4 p = tile[j];  // ds_read_b128 broadcast; fine-grained lgkmcnt
#pragma unroll
    for (int i = 0; i < QPT; i++) {
      // key = 0.5||p||^2 - q.p  (per-query shift by -hq preserves order)
      float t = fmaf(nqx[i], p.x, p.w);
      t = fmaf(nqy[i], p.y, t);
      t = fmaf(nqz[i], p.z, t);
      m2[i] = __builtin_amdgcn_fmed3f(t, m1[i], m2[i]);  // uses old m1
      m1[i] = fminf(m1[i], t);
    }
  }

#pragma unroll
  for (int i = 0; i < QPT; i++) {
    int q = qchunk * QB + threadIdx.x + i * BLOCK;
    pairs[(size_t)s * BN + b * NN + q] =
        make_float2(m1[i] + hq[i], m2[i] + hq[i]);  // un-shift -> d2/2
  }
}

// merge: one thread per point; 256 blocks x 128 threads.
#define MBLK 128
#define NPART (BN / MBLK)  // 256
template <int NSEG>
__global__ __launch_bounds__(MBLK) void merge_kernel(
    const float2* __restrict__ pairs, float* __restrict__ dsum,
    float* __restrict__ partial) {
  int g = blockIdx.x * MBLK + threadIdx.x;  // 0 .. BN-1
  float m1 = BIGF, m2 = BIGF;
#pragma unroll 8
  for (int s = 0; s < NSEG; s++) {
    float2 p = pairs[(size_t)s * BN + g];
    float n2 = __builtin_amdgcn_fmed3f(p.x, m1, m2);
    m1 = fminf(m1, p.x);
    m2 = n2;
    n2 = __builtin_amdgcn_fmed3f(p.y, m1, m2);
    m1 = fminf(m1, p.y);
    m2 = n2;
  }
  float ds = sqrtf(fmaxf(m1 + m1, EPSF)) + sqrtf(fmaxf(m2 + m2, EPSF));
  dsum[g] = ds;

  float v = ds;
#pragma unroll
  for (int off = 32; off > 0; off >>= 1) v += __shfl_down(v, off, 64);
  __shared__ float warp_sums[MBLK / 64];
  if ((threadIdx.x & 63) == 0) warp_sums[threadIdx.x >> 6] = v;
  __syncthreads();
  if (threadIdx.x == 0) {
    float t = 0.0f;
#pragma unroll
    for (int w = 0; w < MBLK / 64; w++) t += warp_sums[w];
    partial[blockIdx.x] = t;
  }
}

// loss: single block of 1024 threads.
#define LBLK 1024
__global__ __launch_bounds__(LBLK) void loss_kernel(
    const float* __restrict__ dsum, const float* __restrict__ partial,
    float* __restrict__ out) {
  __shared__ float s_avg[BB];
  if (threadIdx.x < NPART) {
    float v = partial[threadIdx.x];  // 64 consecutive partials per batch
#pragma unroll
    for (int off = 32; off > 0; off >>= 1) v += __shfl_down(v, off, 64);
    if ((threadIdx.x & 63) == 0) s_avg[threadIdx.x >> 6] = v * (ALPHA / NN);
  }
  __syncthreads();

  const float4* d4 = (const float4*)dsum;
  float acc = 0.0f;
#pragma unroll
  for (int it = 0; it < BN / (LBLK * 4); it++) {
    int idx = it * LBLK + threadIdx.x;  // float4 index
    float4 v = d4[idx];
    float thr = s_avg[idx >> 11];       // 2048 float4 per batch
    acc += (v.x > thr) ? v.x : 0.0f;
    acc += (v.y > thr) ? v.y : 0.0f;
    acc += (v.z > thr) ? v.z : 0.0f;
    acc += (v.w > thr) ? v.w : 0.0f;
  }
#pragma unroll
  for (int off = 32; off > 0; off >>= 1) acc += __shfl_down(acc, off, 64);
  __shared__ float warp_sums[LBLK / 64];
  if ((threadIdx.x & 63) == 0) warp_sums[threadIdx.x >> 6] = acc;
  __syncthreads();
  if (threadIdx.x == 0) {
    float t = 0.0f;
#pragma unroll
    for (int w = 0; w < LBLK / 64; w++) t += warp_sums[w];
    out[0] = t;
  }
}

template <int NSEG>
static void run(const float* xyz, float* out, void* d_ws, hipStream_t stream) {
  float2* pairs = (float2*)d_ws;
  float4* refs4 = (float4*)(pairs + (size_t)NSEG * BN);
  float* dsum = (float*)(refs4 + BN);
  float* partial = dsum + BN;
  prep_kernel<<<BN / BLOCK, BLOCK, 0, stream>>>(xyz, refs4);
  int grid1 = BB * (NN / QB) * NSEG;
  knn_kernel<NSEG><<<grid1, BLOCK, 0, stream>>>(refs4, pairs);
  merge_kernel<NSEG><<<BN / MBLK, MBLK, 0, stream>>>(pairs, dsum, partial);
  loss_kernel<<<1, LBLK, 0, stream>>>(dsum, partial, out);
}

extern "C" void kernel_launch(void* const* d_in, const int* in_sizes, int n_in,
                              void* d_out, int out_size, void* d_ws,
                              size_t ws_size, hipStream_t stream) {
  const float* xyz = (const float*)d_in[0];
  float* out = (float*)d_out;

  auto need = [](int nseg) {
    return (size_t)nseg * BN * sizeof(float2) + BN * sizeof(float4) +
           BN * sizeof(float) + NPART * sizeof(float);
  };
  if (ws_size >= need(64)) {
    run<64>(xyz, out, d_ws, stream);  // grid1 = 512 blocks
  } else if (ws_size >= need(32)) {
    run<32>(xyz, out, d_ws, stream);
  } else {
    run<16>(xyz, out, d_ws, stream);
  }
}

// Round 9
// 102.290 us; speedup vs baseline: 1.0549x; 1.0345x over previous
//
#include <hip/hip_runtime.h>

#define BB 4
#define NN 8192
#define BN (BB * NN)
#define ALPHA 5.0f
#define EPSF 1e-12f
#define BLOCK 256
#define QPT 8              // queries per thread (faithful at this VGPR budget)
#define QB (BLOCK * QPT)   // 2048 queries per block
#define BIGF 1e30f

// prep: refs4[g] = (x, y, z, 0.5*||p||^2)
__global__ __launch_bounds__(BLOCK) void prep_kernel(
    const float* __restrict__ xyz, float4* __restrict__ refs4) {
  int g = blockIdx.x * BLOCK + threadIdx.x;  // 0..BN-1
  float x = xyz[3 * g + 0], y = xyz[3 * g + 1], z = xyz[3 * g + 2];
  float hpp = 0.5f * fmaf(x, x, fmaf(y, y, z * z));
  refs4[g] = make_float4(x, y, z, hpp);
}

// pairs layout: pairs[s * BN + b*NN + q]   (values are d2/2)
// SoA LDS: one ds_read_b128 delivers 4 refs of one component -> 3 LDS
// instructions per 4 refs (4x fewer than AoS float4/ref).
template <int NSEG>
__global__ __launch_bounds__(BLOCK, 4) void knn_kernel(
    const float4* __restrict__ refs4, float2* __restrict__ pairs) {
  constexpr int SEG = NN / NSEG;   // 128 at NSEG=64
  constexpr int CHUNKS = NN / QB;  // 4
  int bid = blockIdx.x;
  int s = bid % NSEG;
  int rem = bid / NSEG;
  int qchunk = rem % CHUNKS;
  int b = rem / CHUNKS;

  const float4* __restrict__ qb4 = refs4 + (size_t)b * NN;

  __shared__ float sx[SEG], sy[SEG], sz[SEG];
  for (int r = threadIdx.x; r < SEG; r += BLOCK) {
    float4 v = qb4[s * SEG + r];
    sx[r] = v.x;
    sy[r] = v.y;
    sz[r] = v.z;
  }

  float nqx[QPT], nqy[QPT], nqz[QPT], hq[QPT], m1[QPT], m2[QPT];
#pragma unroll
  for (int i = 0; i < QPT; i++) {
    int q = qchunk * QB + threadIdx.x + i * BLOCK;
    float4 qp = qb4[q];  // coalesced vector load
    nqx[i] = -qp.x;
    nqy[i] = -qp.y;
    nqz[i] = -qp.z;
    hq[i] = qp.w;
    m1[i] = BIGF;
    m2[i] = BIGF;
  }
  __syncthreads();

#pragma unroll 1
  for (int j = 0; j < SEG; j += 4) {
    float4 px = *(const float4*)&sx[j];  // 4 refs' x (broadcast b128)
    float4 py = *(const float4*)&sy[j];
    float4 pz = *(const float4*)&sz[j];
    float rx[4] = {px.x, px.y, px.z, px.w};
    float ry[4] = {py.x, py.y, py.z, py.w};
    float rz[4] = {pz.x, pz.y, pz.z, pz.w};
#pragma unroll
    for (int k = 0; k < 4; k++) {
      float w = 0.5f * fmaf(rx[k], rx[k], fmaf(ry[k], ry[k], rz[k] * rz[k]));
#pragma unroll
      for (int i = 0; i < QPT; i++) {
        // key = 0.5||p||^2 - q.p  (per-query shift by -hq preserves order)
        float t = fmaf(nqx[i], rx[k], w);
        t = fmaf(nqy[i], ry[k], t);
        t = fmaf(nqz[i], rz[k], t);
        m2[i] = __builtin_amdgcn_fmed3f(t, m1[i], m2[i]);  // uses old m1
        m1[i] = fminf(m1[i], t);
      }
    }
  }

#pragma unroll
  for (int i = 0; i < QPT; i++) {
    int q = qchunk * QB + threadIdx.x + i * BLOCK;
    pairs[(size_t)s * BN + b * NN + q] =
        make_float2(m1[i] + hq[i], m2[i] + hq[i]);  // un-shift -> d2/2
  }
}

// merge: one thread per point; 256 blocks x 128 threads.
#define MBLK 128
#define NPART (BN / MBLK)  // 256
template <int NSEG>
__global__ __launch_bounds__(MBLK) void merge_kernel(
    const float2* __restrict__ pairs, float* __restrict__ dsum,
    float* __restrict__ partial) {
  int g = blockIdx.x * MBLK + threadIdx.x;  // 0 .. BN-1
  float m1 = BIGF, m2 = BIGF;
#pragma unroll 8
  for (int s = 0; s < NSEG; s++) {
    float2 p = pairs[(size_t)s * BN + g];
    float n2 = __builtin_amdgcn_fmed3f(p.x, m1, m2);
    m1 = fminf(m1, p.x);
    m2 = n2;
    n2 = __builtin_amdgcn_fmed3f(p.y, m1, m2);
    m1 = fminf(m1, p.y);
    m2 = n2;
  }
  float ds = sqrtf(fmaxf(m1 + m1, EPSF)) + sqrtf(fmaxf(m2 + m2, EPSF));
  dsum[g] = ds;

  float v = ds;
#pragma unroll
  for (int off = 32; off > 0; off >>= 1) v += __shfl_down(v, off, 64);
  __shared__ float warp_sums[MBLK / 64];
  if ((threadIdx.x & 63) == 0) warp_sums[threadIdx.x >> 6] = v;
  __syncthreads();
  if (threadIdx.x == 0) {
    float t = 0.0f;
#pragma unroll
    for (int w = 0; w < MBLK / 64; w++) t += warp_sums[w];
    partial[blockIdx.x] = t;
  }
}

// loss: single block of 1024 threads.
#define LBLK 1024
__global__ __launch_bounds__(LBLK) void loss_kernel(
    const float* __restrict__ dsum, const float* __restrict__ partial,
    float* __restrict__ out) {
  __shared__ float s_avg[BB];
  if (threadIdx.x < NPART) {
    float v = partial[threadIdx.x];  // 64 consecutive partials per batch
#pragma unroll
    for (int off = 32; off > 0; off >>= 1) v += __shfl_down(v, off, 64);
    if ((threadIdx.x & 63) == 0) s_avg[threadIdx.x >> 6] = v * (ALPHA / NN);
  }
  __syncthreads();

  const float4* d4 = (const float4*)dsum;
  float acc = 0.0f;
#pragma unroll
  for (int it = 0; it < BN / (LBLK * 4); it++) {
    int idx = it * LBLK + threadIdx.x;  // float4 index
    float4 v = d4[idx];
    float thr = s_avg[idx >> 11];       // 2048 float4 per batch
    acc += (v.x > thr) ? v.x : 0.0f;
    acc += (v.y > thr) ? v.y : 0.0f;
    acc += (v.z > thr) ? v.z : 0.0f;
    acc += (v.w > thr) ? v.w : 0.0f;
  }
#pragma unroll
  for (int off = 32; off > 0; off >>= 1) acc += __shfl_down(acc, off, 64);
  __shared__ float warp_sums[LBLK / 64];
  if ((threadIdx.x & 63) == 0) warp_sums[threadIdx.x >> 6] = acc;
  __syncthreads();
  if (threadIdx.x == 0) {
    float t = 0.0f;
#pragma unroll
    for (int w = 0; w < LBLK / 64; w++) t += warp_sums[w];
    out[0] = t;
  }
}

template <int NSEG>
static void run(const float* xyz, float* out, void* d_ws, hipStream_t stream) {
  float2* pairs = (float2*)d_ws;
  float4* refs4 = (float4*)(pairs + (size_t)NSEG * BN);
  float* dsum = (float*)(refs4 + BN);
  float* partial = dsum + BN;
  prep_kernel<<<BN / BLOCK, BLOCK, 0, stream>>>(xyz, refs4);
  int grid1 = BB * (NN / QB) * NSEG;
  knn_kernel<NSEG><<<grid1, BLOCK, 0, stream>>>(refs4, pairs);
  merge_kernel<NSEG><<<BN / MBLK, MBLK, 0, stream>>>(pairs, dsum, partial);
  loss_kernel<<<1, LBLK, 0, stream>>>(dsum, partial, out);
}

extern "C" void kernel_launch(void* const* d_in, const int* in_sizes, int n_in,
                              void* d_out, int out_size, void* d_ws,
                              size_t ws_size, hipStream_t stream) {
  const float* xyz = (const float*)d_in[0];
  float* out = (float*)d_out;

  auto need = [](int nseg) {
    return (size_t)nseg * BN * sizeof(float2) + BN * sizeof(float4) +
           BN * sizeof(float) + NPART * sizeof(float);
  };
  if (ws_size >= need(64)) {
    run<64>(xyz, out, d_ws, stream);  // grid1 = 1024 blocks, 4/CU
  } else if (ws_size >= need(32)) {
    run<32>(xyz, out, d_ws, stream);
  } else {
    run<16>(xyz, out, d_ws, stream);
  }
}

// Round 10
// 100.542 us; speedup vs baseline: 1.0732x; 1.0174x over previous
//
#include <hip/hip_runtime.h>

#define BB 4
#define NN 8192
#define BN (BB * NN)
#define ALPHA 5.0f
#define EPSF 1e-12f
#define BLOCK 256
#define QPT 8              // queries per thread
#define QB (BLOCK * QPT)   // 2048 queries per block
#define BIGF 1e30f

// prep: refs4[g] = (x, y, z, 0.5*||p||^2)
__global__ __launch_bounds__(BLOCK) void prep_kernel(
    const float* __restrict__ xyz, float4* __restrict__ refs4) {
  int g = blockIdx.x * BLOCK + threadIdx.x;  // 0..BN-1
  float x = xyz[3 * g + 0], y = xyz[3 * g + 1], z = xyz[3 * g + 2];
  float hpp = 0.5f * fmaf(x, x, fmaf(y, y, z * z));
  refs4[g] = make_float4(x, y, z, hpp);
}

// pairs layout: pairs[s * BN + b*NN + q]   (values are d2/2)
// Inner loop is STAGE-SPLIT across queries: all fma1's, all fma2's, ... so
// 8 independent dependency chains are live at once (hides 4-cyc VALU
// latency). launch_bounds(256,2) gives the allocator register headroom so
// it cannot serialize the chains to save VGPRs.
template <int NSEG>
__global__ __launch_bounds__(BLOCK, 2) void knn_kernel(
    const float4* __restrict__ refs4, float2* __restrict__ pairs) {
  constexpr int SEG = NN / NSEG;   // 128 at NSEG=64
  constexpr int CHUNKS = NN / QB;  // 4
  int bid = blockIdx.x;
  int s = bid % NSEG;
  int rem = bid / NSEG;
  int qchunk = rem % CHUNKS;
  int b = rem / CHUNKS;

  const float4* __restrict__ qb4 = refs4 + (size_t)b * NN;

  __shared__ float sx[SEG], sy[SEG], sz[SEG], sw[SEG];
  for (int r = threadIdx.x; r < SEG; r += BLOCK) {
    float4 v = qb4[s * SEG + r];
    sx[r] = v.x;
    sy[r] = v.y;
    sz[r] = v.z;
    sw[r] = v.w;
  }

  float nqx[QPT], nqy[QPT], nqz[QPT], hq[QPT], m1[QPT], m2[QPT];
#pragma unroll
  for (int i = 0; i < QPT; i++) {
    int q = qchunk * QB + threadIdx.x + i * BLOCK;
    float4 qp = qb4[q];  // coalesced vector load
    nqx[i] = -qp.x;
    nqy[i] = -qp.y;
    nqz[i] = -qp.z;
    hq[i] = qp.w;
    m1[i] = BIGF;
    m2[i] = BIGF;
  }
  __syncthreads();

#pragma unroll 1
  for (int j = 0; j < SEG; j += 4) {
    float4 px = *(const float4*)&sx[j];  // 4 refs' x (broadcast b128)
    float4 py = *(const float4*)&sy[j];
    float4 pz = *(const float4*)&sz[j];
    float4 pw = *(const float4*)&sw[j];
    float rx[4] = {px.x, px.y, px.z, px.w};
    float ry[4] = {py.x, py.y, py.z, py.w};
    float rz[4] = {pz.x, pz.y, pz.z, pz.w};
    float rw[4] = {pw.x, pw.y, pw.z, pw.w};
#pragma unroll
    for (int k = 0; k < 4; k++) {
      float t[QPT];
      // stage 1..3: 8 independent fma chains, interleaved by construction
#pragma unroll
      for (int i = 0; i < QPT; i++) t[i] = fmaf(nqx[i], rx[k], rw[k]);
#pragma unroll
      for (int i = 0; i < QPT; i++) t[i] = fmaf(nqy[i], ry[k], t[i]);
#pragma unroll
      for (int i = 0; i < QPT; i++) t[i] = fmaf(nqz[i], rz[k], t[i]);
#pragma unroll
      for (int i = 0; i < QPT; i++)
        m2[i] = __builtin_amdgcn_fmed3f(t[i], m1[i], m2[i]);  // old m1
#pragma unroll
      for (int i = 0; i < QPT; i++) m1[i] = fminf(m1[i], t[i]);
    }
  }

#pragma unroll
  for (int i = 0; i < QPT; i++) {
    int q = qchunk * QB + threadIdx.x + i * BLOCK;
    pairs[(size_t)s * BN + b * NN + q] =
        make_float2(m1[i] + hq[i], m2[i] + hq[i]);  // un-shift -> d2/2
  }
}

// merge: one thread per point; 256 blocks x 128 threads.
#define MBLK 128
#define NPART (BN / MBLK)  // 256
template <int NSEG>
__global__ __launch_bounds__(MBLK) void merge_kernel(
    const float2* __restrict__ pairs, float* __restrict__ dsum,
    float* __restrict__ partial) {
  int g = blockIdx.x * MBLK + threadIdx.x;  // 0 .. BN-1
  float m1 = BIGF, m2 = BIGF;
#pragma unroll 8
  for (int s = 0; s < NSEG; s++) {
    float2 p = pairs[(size_t)s * BN + g];
    float n2 = __builtin_amdgcn_fmed3f(p.x, m1, m2);
    m1 = fminf(m1, p.x);
    m2 = n2;
    n2 = __builtin_amdgcn_fmed3f(p.y, m1, m2);
    m1 = fminf(m1, p.y);
    m2 = n2;
  }
  float ds = sqrtf(fmaxf(m1 + m1, EPSF)) + sqrtf(fmaxf(m2 + m2, EPSF));
  dsum[g] = ds;

  float v = ds;
#pragma unroll
  for (int off = 32; off > 0; off >>= 1) v += __shfl_down(v, off, 64);
  __shared__ float warp_sums[MBLK / 64];
  if ((threadIdx.x & 63) == 0) warp_sums[threadIdx.x >> 6] = v;
  __syncthreads();
  if (threadIdx.x == 0) {
    float t = 0.0f;
#pragma unroll
    for (int w = 0; w < MBLK / 64; w++) t += warp_sums[w];
    partial[blockIdx.x] = t;
  }
}

// loss: single block of 1024 threads.
#define LBLK 1024
__global__ __launch_bounds__(LBLK) void loss_kernel(
    const float* __restrict__ dsum, const float* __restrict__ partial,
    float* __restrict__ out) {
  __shared__ float s_avg[BB];
  if (threadIdx.x < NPART) {
    float v = partial[threadIdx.x];  // 64 consecutive partials per batch
#pragma unroll
    for (int off = 32; off > 0; off >>= 1) v += __shfl_down(v, off, 64);
    if ((threadIdx.x & 63) == 0) s_avg[threadIdx.x >> 6] = v * (ALPHA / NN);
  }
  __syncthreads();

  const float4* d4 = (const float4*)dsum;
  float acc = 0.0f;
#pragma unroll
  for (int it = 0; it < BN / (LBLK * 4); it++) {
    int idx = it * LBLK + threadIdx.x;  // float4 index
    float4 v = d4[idx];
    float thr = s_avg[idx >> 11];       // 2048 float4 per batch
    acc += (v.x > thr) ? v.x : 0.0f;
    acc += (v.y > thr) ? v.y : 0.0f;
    acc += (v.z > thr) ? v.z : 0.0f;
    acc += (v.w > thr) ? v.w : 0.0f;
  }
#pragma unroll
  for (int off = 32; off > 0; off >>= 1) acc += __shfl_down(acc, off, 64);
  __shared__ float warp_sums[LBLK / 64];
  if ((threadIdx.x & 63) == 0) warp_sums[threadIdx.x >> 6] = acc;
  __syncthreads();
  if (threadIdx.x == 0) {
    float t = 0.0f;
#pragma unroll
    for (int w = 0; w < LBLK / 64; w++) t += warp_sums[w];
    out[0] = t;
  }
}

template <int NSEG>
static void run(const float* xyz, float* out, void* d_ws, hipStream_t stream) {
  float2* pairs = (float2*)d_ws;
  float4* refs4 = (float4*)(pairs + (size_t)NSEG * BN);
  float* dsum = (float*)(refs4 + BN);
  float* partial = dsum + BN;
  prep_kernel<<<BN / BLOCK, BLOCK, 0, stream>>>(xyz, refs4);
  int grid1 = BB * (NN / QB) * NSEG;
  knn_kernel<NSEG><<<grid1, BLOCK, 0, stream>>>(refs4, pairs);
  merge_kernel<NSEG><<<BN / MBLK, MBLK, 0, stream>>>(pairs, dsum, partial);
  loss_kernel<<<1, LBLK, 0, stream>>>(dsum, partial, out);
}

extern "C" void kernel_launch(void* const* d_in, const int* in_sizes, int n_in,
                              void* d_out, int out_size, void* d_ws,
                              size_t ws_size, hipStream_t stream) {
  const float* xyz = (const float*)d_in[0];
  float* out = (float*)d_out;

  auto need = [](int nseg) {
    return (size_t)nseg * BN * sizeof(float2) + BN * sizeof(float4) +
           BN * sizeof(float) + NPART * sizeof(float);
  };
  if (ws_size >= need(64)) {
    run<64>(xyz, out, d_ws, stream);  // grid1 = 1024 blocks, 4/CU
  } else if (ws_size >= need(32)) {
    run<32>(xyz, out, d_ws, stream);
  } else {
    run<16>(xyz, out, d_ws, stream);
  }
}